// Round 13
// baseline (246.771 us; speedup 1.0000x reference)
//
#include <hip/hip_runtime.h>
#include <hip/hip_bf16.h>

typedef unsigned short u16;
typedef unsigned int   u32;

using bf16x8 = __attribute__((ext_vector_type(8))) short;   // 8 bf16 in 4 VGPRs
using f32x4  = __attribute__((ext_vector_type(4))) float;
using f32x16 = __attribute__((ext_vector_type(16))) float;  // 32x32 MFMA acc

#define NB 32
#define NP 1024
#define ND 256

__device__ __forceinline__ u16 f2bf(float x){
  u32 u = __float_as_uint(x);
  u += 0x7FFFu + ((u >> 16) & 1u);   // round-to-nearest-even
  return (u16)(u >> 16);
}

__device__ __forceinline__ float bf2f(u16 x){
  return __uint_as_float((u32)x << 16);
}

__device__ __forceinline__ u32 packbf(float a, float b){
  return (u32)f2bf(a) | ((u32)f2bf(b) << 16);
}

__device__ __forceinline__ void glds16(const void* g, void* l){
  __builtin_amdgcn_global_load_lds((const __attribute__((address_space(1))) void*)g,
                                   (__attribute__((address_space(3))) void*)l, 16, 0, 0);
}

// ---------------- prep 1: Pbf = bf16(P), sbv[row] = P[row,:] . wb ----------------
__global__ void prep_rows(const float* __restrict__ P, const float* __restrict__ wi,
                          u16* __restrict__ Pbf, float* __restrict__ sbv){
  const int row  = blockIdx.x * 4 + (threadIdx.x >> 6);   // one wave per row
  const int lane = threadIdx.x & 63;
  const float4 p  = *(const float4*)(P  + (size_t)row * ND + lane * 4);
  const float4 wb = *(const float4*)(wi + ND + lane * 4);  // wb = wi[256:512]
  ushort4 pb;
  pb.x = f2bf(p.x); pb.y = f2bf(p.y); pb.z = f2bf(p.z); pb.w = f2bf(p.w);
  *(ushort4*)(Pbf + (size_t)row * ND + lane * 4) = pb;
  float s = p.x*wb.x + p.y*wb.y + p.z*wb.z + p.w*wb.w;
  #pragma unroll
  for (int m = 1; m < 64; m <<= 1) s += __shfl_xor(s, m, 64);
  if (lane == 0) sbv[row] = s;
}

// ------- prep 2: pack W fragment-major: Wp[((t*16+c)*64+lane)*8 + e] -------------
__global__ void prep_w(const float* __restrict__ w1, const float* __restrict__ w2,
                       const float* __restrict__ w3, u16* __restrict__ Wp){
  const int t = blockIdx.x;                       // 0..47
  const float* w = (t < 16) ? w1 : ((t < 32) ? w2 : w3);
  const int tid = threadIdx.x;
  #pragma unroll
  for (int j = 0; j < 4; ++j){
    int item = tid + 256 * j;                     // c*64 + lane
    int c = item >> 6, lane = item & 63;
    int ncol = ((t & 15) << 4) + (lane & 15);
    int k0 = 32 * c + 8 * (lane >> 4);
    u16 tmp[8];
    #pragma unroll
    for (int e = 0; e < 8; ++e) tmp[e] = f2bf(w[(size_t)(k0 + e) * 256 + ncol]);
    *(uint4*)(Wp + ((size_t)(t * 16 + c) * 64 + lane) * 8) = *(uint4*)tmp;
  }
}

// ---------------- prep 3: PbfT[b][d][j] = Pbf[b][j][d] (64x64 LDS tiles) ---------
__global__ void transpose_p(const u16* __restrict__ Pbf, u16* __restrict__ PbfT){
  const int b = blockIdx.z, jt = blockIdx.x, dt = blockIdx.y;
  __shared__ u16 T[64][72];
  const int tid = threadIdx.x;
  #pragma unroll
  for (int it = 0; it < 2; ++it){
    int cc = tid + 256 * it;               // 0..511: 64 j-rows x 8 chunks
    int j = cc >> 3, c8 = cc & 7;
    uint4 v = *(const uint4*)(Pbf + ((size_t)b * NP + jt * 64 + j) * ND + dt * 64 + c8 * 8);
    *(uint4*)&T[j][c8 * 8] = v;
  }
  __syncthreads();
  #pragma unroll
  for (int it = 0; it < 2; ++it){
    int cc = tid + 256 * it;               // 64 d-rows x 8 chunks
    int d = cc >> 3, c8 = cc & 7;
    u16 tmp[8];
    #pragma unroll
    for (int k = 0; k < 8; ++k) tmp[k] = T[c8 * 8 + k][d];
    *(uint4*)(PbfT + ((size_t)b * ND + dt * 64 + d) * NP + jt * 64 + c8 * 8) = *(uint4*)tmp;
  }
}

// ------------- attention: 32x32 MFMA swapped, 2-wave blocks, QBLK=64, KBLK=32 ----
// Wave owns 32 q-rows. S^T = mfma_32x32x16(K_frag, Q_frag): C row=j, col=q.
// PV A-frag (P) is half in-lane (regs 8jt..8jt+7), half from lane^32 (2 shfl_xor
// pairs) -> NO Sp LDS repack (the 4.45M-conflict source). LDS frag traffic /4 vs
// r10 (8KB QK + 8KB PV per wave-tile for 32 q). Layouts (validated bijection
// rule, 16B-quad granularity):
//   K: phys = j*512 + 16*(u ^ (j&7)), u = d>>3   -> read quad (2ks+hi2)^(j&7): clean
//   V: phys = d*64  + 16*(u ^ (d&3)), u = j>>3   -> read 2-way (free, m136)
// glds sources = within-row 16B permutations (coalesced). Split barriers as r10.
// 512 blocks, 4 independent 2-wave domains/CU (r11's desync WITHOUT its staging
// penalty: QBLK stays 64). VGPR ~240 (of=128,qf=64) under (128,2)'s 256 budget.
__launch_bounds__(128, 2)
__global__ void attn_kernel(const float* __restrict__ P, const float* __restrict__ wi,
                            const u16* __restrict__ Pbf, const u16* __restrict__ PbfT,
                            const float* __restrict__ sbv, u16* __restrict__ attnb){
  const int p    = blockIdx.x;
  const int bid  = ((p & 7) << 6) | (p >> 3);     // 64 consecutive bids per XCD
  const int b    = bid >> 4;
  const int q0   = (bid & 15) << 6;
  const int tid  = threadIdx.x;
  const int wave = tid >> 6, lane = tid & 63;
  const int q    = lane & 31, hi2 = lane >> 5;

  __shared__ __align__(16) u16 KtA[32 * 256];     // 16 KB
  __shared__ __align__(16) u16 VtA[256 * 32];     // 16 KB
  char* KtB = (char*)KtA;
  char* VtB = (char*)VtA;

  // ---- Q fragments (B-operand): qf[ks][e] = P[qrow][16ks+8hi2+e]*wc ----
  bf16x8 qf[16];
  {
    const int qrow = q0 + 32 * wave + q;
    const float* prow = P  + ((size_t)b * NP + qrow) * ND;
    const float* wcp  = wi + 512;
    #pragma unroll
    for (int ks = 0; ks < 16; ++ks){
      const int d0 = 16 * ks + 8 * hi2;
      float4 a  = *(const float4*)(prow + d0);
      float4 a2 = *(const float4*)(prow + d0 + 4);
      float4 wa  = *(const float4*)(wcp + d0);
      float4 wa2 = *(const float4*)(wcp + d0 + 4);
      bf16x8 qv;
      qv[0]=(short)f2bf(a.x*wa.x);  qv[1]=(short)f2bf(a.y*wa.y);
      qv[2]=(short)f2bf(a.z*wa.z);  qv[3]=(short)f2bf(a.w*wa.w);
      qv[4]=(short)f2bf(a2.x*wa2.x); qv[5]=(short)f2bf(a2.y*wa2.y);
      qv[6]=(short)f2bf(a2.z*wa2.z); qv[7]=(short)f2bf(a2.w*wa2.w);
      qf[ks] = qv;
    }
  }

  f32x16 of[8];
  #pragma unroll
  for (int dt = 0; dt < 8; ++dt)
    #pragma unroll
    for (int r = 0; r < 16; ++r) of[dt][r] = 0.f;
  float mx = -1e30f;     // running max of row q (shared by lanes q, q+32)
  float ls = 0.f;        // lane-partial softmax sum for row q

  const u16* kslab = Pbf  + (size_t)b * NP * ND;   // row-major [j][d]
  const u16* vslab = PbfT + (size_t)b * ND * NP;   // d-major  [d][j]

  auto stageK = [&](int kt){
    const int kbase = kt * 32;
    #pragma unroll
    for (int it = 0; it < 8; ++it){
      int off = it * 2048 + tid * 16;             // linear LDS dest byte
      int j   = off >> 9;                          // key row 0..31
      int u   = (off >> 4) & 31;                   // phys 16B unit in row
      int d0  = 8 * (u ^ (j & 7));                 // logical d base
      glds16((const char*)(kslab + (size_t)(kbase + j) * ND + d0), KtB + off);
    }
  };
  auto stageV = [&](int kt){
    const int kbase = kt * 32;
    #pragma unroll
    for (int it = 0; it < 8; ++it){
      int off = it * 2048 + tid * 16;
      int d   = off >> 6;                          // feature row 0..255
      int u   = (off >> 4) & 3;
      int j0  = 8 * (u ^ (d & 3));
      glds16((const char*)(vslab + (size_t)d * NP + kbase + j0), VtB + off);
    }
  };

  stageK(0);
  stageV(0);
  __syncthreads();                                 // drain: K0,V0 valid

  for (int kt = 0; kt < 32; ++kt){
    const int kbase = kt * 32;

    // ---- S^T = K Q (swapped): lane reg r holds S[j=(r&3)+8(r>>2)+4hi2][q] ----
    f32x16 s;
    #pragma unroll
    for (int r = 0; r < 16; ++r) s[r] = 0.f;
    #pragma unroll
    for (int ks = 0; ks < 16; ++ks){
      int ad = q * 512 + (((2 * ks + hi2) ^ (q & 7)) << 4);
      bf16x8 kf = *(const bf16x8*)(KtB + ad);
      s = __builtin_amdgcn_mfma_f32_32x32x16_bf16(kf, qf[ks], s, 0, 0, 0);
    }
    __syncthreads();                  // barrier1: Kt reads done
    if (kt < 31) stageK(kt + 1);      // in flight across softmax+PV; drains at b2

    // ---- add sb[j] ----
    #pragma unroll
    for (int g = 0; g < 4; ++g){
      float4 sq = *(const float4*)(sbv + (size_t)b * NP + kbase + 8 * g + 4 * hi2);
      s[4*g+0] += sq.x; s[4*g+1] += sq.y; s[4*g+2] += sq.z; s[4*g+3] += sq.w;
    }

    // ---- deferred online softmax (row q; lane covers 16 of 32 j) ----
    float vmax = s[0];
    #pragma unroll
    for (int r = 1; r < 16; ++r) vmax = fmaxf(vmax, s[r]);
    if (!__all(vmax - mx <= 8.f)){
      float v = fmaxf(vmax, __shfl_xor(vmax, 32, 64));
      float mnew = fmaxf(mx, v);
      float sc = __expf(mx - mnew);
      mx = mnew; ls *= sc;
      #pragma unroll
      for (int r = 0; r < 16; ++r){
        float scr = __shfl(sc, (r & 3) + 8 * (r >> 2) + 4 * hi2, 64);
        #pragma unroll
        for (int dt = 0; dt < 8; ++dt) of[dt][r] *= scr;
      }
    }
    // common path: exp + lane-partial sum
    float E[16];
    #pragma unroll
    for (int r = 0; r < 16; ++r){ E[r] = __expf(s[r] - mx); ls += E[r]; }

    // ---- build PV A-frags: half in-lane, half from lane^32 ----
    #pragma unroll
    for (int jt = 0; jt < 2; ++jt){
      u32 a0 = packbf(E[8*jt+0], E[8*jt+1]);
      u32 a1 = packbf(E[8*jt+2], E[8*jt+3]);
      u32 b0 = packbf(E[8*jt+4], E[8*jt+5]);
      u32 b1 = packbf(E[8*jt+6], E[8*jt+7]);
      u32 ta0 = __shfl_xor((int)a0, 32, 64);
      u32 ta1 = __shfl_xor((int)a1, 32, 64);
      u32 tb0 = __shfl_xor((int)b0, 32, 64);
      u32 tb1 = __shfl_xor((int)b1, 32, 64);
      union { bf16x8 v; u32 d[4]; } pa;
      pa.d[0] = hi2 ? tb0 : a0;
      pa.d[1] = hi2 ? tb1 : a1;
      pa.d[2] = hi2 ? b0 : ta0;
      pa.d[3] = hi2 ? b1 : ta1;
      // ---- O[:, dt] += P V ----
      #pragma unroll
      for (int dt = 0; dt < 8; ++dt){
        int d  = 32 * dt + q;
        int ad = d * 64 + (((2 * jt + hi2) ^ (d & 3)) << 4);
        bf16x8 vb = *(const bf16x8*)(VtB + ad);
        of[dt] = __builtin_amdgcn_mfma_f32_32x32x16_bf16(pa.v, vb, of[dt], 0, 0, 0);
      }
    }

    __syncthreads();                  // barrier2: Vt reads done; drains K(t+1)
    if (kt < 31) stageV(kt + 1);      // in flight across next QK^T; drains at b1
  }

  // ---- epilogue: row-sum (1 shfl), O /= l, store bf16 ----
  ls += __shfl_xor(ls, 32, 64);
  const int qb = q0 + 32 * wave;
  #pragma unroll
  for (int r = 0; r < 16; ++r){
    const int qr = (r & 3) + 8 * (r >> 2) + 4 * hi2;
    float lr = __shfl(ls, qr, 64);
    #pragma unroll
    for (int dt = 0; dt < 8; ++dt){
      float o = of[dt][r] / lr;
      attnb[((size_t)b * NP + qb + qr) * ND + 32 * dt + q] = f2bf(o);
    }
  }
}

// ---------------- MLP: proper GEMM, M-tile 128, fused gate epilogue --------------
// NOTE: acc[3][8] = 96 VGPRs of accumulator. __launch_bounds__ min-waves MUST stay
// at 2 (VGPR budget 256): round-5's (256,4) capped the allocator at 64 VGPR and
// spilled all accumulators to scratch (WRITE_SIZE 33 -> 325 MB, 18 -> 136 us).
__launch_bounds__(256, 2)
__global__ void mlp_kernel(const u16* __restrict__ Pbf, const u16* __restrict__ attnb,
                           const u16* __restrict__ Wp,
                           const float* __restrict__ b1, const float* __restrict__ b2,
                           const float* __restrict__ b3, float* __restrict__ out){
  const int p    = blockIdx.x;
  const int swz  = ((p & 7) << 7) | (p >> 3);     // XCD-chunked
  const int mt   = swz >> 2, cg = swz & 3;
  const int tid  = threadIdx.x;
  const int wave = tid >> 6, lane = tid & 63, lo = lane & 15, hi = lane >> 4;
  const int tq   = 4 * cg + wave;
  const int m0   = mt * 128;

  __shared__ __align__(16) u16 Ab[2][128 * 64];   // 2 x 16 KB, swizzled

  f32x4 acc[3][8];
  #pragma unroll
  for (int e = 0; e < 3; ++e)
    #pragma unroll
    for (int m = 0; m < 8; ++m) acc[e][m] = (f32x4){0.f,0.f,0.f,0.f};

  auto stage = [&](int s, int buf){
    const u16* xs = (s < 4) ? (Pbf   + (size_t)m0 * ND + s * 64)
                            : (attnb + (size_t)m0 * ND + (s - 4) * 64);
    char* dst = (char*)Ab[buf];
    #pragma unroll
    for (int it = 0; it < 4; ++it){
      int off = it * 4096 + wave * 1024 + lane * 16;   // physical LDS byte
      int row = off >> 7;                               // 128B per row
      int cl  = (off & 127) ^ ((row & 7) << 4);         // logical byte in row
      glds16((const char*)(xs + (size_t)row * ND) + cl, dst + it * 4096 + wave * 1024);
    }
  };

  stage(0, 0);
  __syncthreads();

  for (int s = 0; s < 8; ++s){
    if (s < 7) stage(s + 1, (s + 1) & 1);
    const char* ab = (const char*)Ab[s & 1];
    #pragma unroll
    for (int cc = 0; cc < 2; ++cc){
      const int c = 2 * s + cc;
      bf16x8 wf[3];
      #pragma unroll
      for (int e = 0; e < 3; ++e)
        wf[e] = *(const bf16x8*)(Wp + ((size_t)((tq + 16 * e) * 16 + c) * 64 + lane) * 8);
      #pragma unroll
      for (int m = 0; m < 8; ++m){
        int row = 16 * m + lo;
        bf16x8 af = *(const bf16x8*)(ab + row * 128 + ((64 * cc + 16 * hi) ^ ((row & 7) << 4)));
        #pragma unroll
        for (int e = 0; e < 3; ++e)
          acc[e][m] = __builtin_amdgcn_mfma_f32_16x16x32_bf16(af, wf[e], acc[e][m], 0, 0, 0);
      }
    }
    __syncthreads();
  }

  // ---- fused gate epilogue ----
  const int d = 16 * tq + lo;
  const float bb1 = b1[d], bb2 = b2[d], bb3 = b3[d];
  #pragma unroll
  for (int m = 0; m < 8; ++m){
    #pragma unroll
    for (int r = 0; r < 4; ++r){
      const int row = m0 + 16 * m + 4 * hi + r;
      float y1 = acc[0][m][r] + bb1;
      float y2 = acc[1][m][r] + bb2;
      float y3 = acc[2][m][r] + bb3;
      float pv = bf2f(Pbf[(size_t)row * ND + d]);
      float e2 = __expf(2.f * y1);
      float z  = (e2 - 1.f) / (e2 + 1.f);          // tanh
      float rr = 1.f / (1.f + __expf(-y2));        // sigmoid
      float ff = 1.f / (1.f + __expf(-y3));        // sigmoid
      out[(size_t)row * ND + d] = rr * pv + ff * z;
    }
  }
}

extern "C" void kernel_launch(void* const* d_in, const int* in_sizes, int n_in,
                              void* d_out, int out_size, void* d_ws, size_t ws_size,
                              hipStream_t stream){
  const float* P  = (const float*)d_in[0];
  const float* wi = (const float*)d_in[1];
  const float* w1 = (const float*)d_in[2];
  const float* w2 = (const float*)d_in[3];
  const float* w3 = (const float*)d_in[4];
  const float* b1 = (const float*)d_in[5];
  const float* b2 = (const float*)d_in[6];
  const float* b3 = (const float*)d_in[7];
  float* out = (float*)d_out;

  char* ws = (char*)d_ws;
  u16*   Pbf   = (u16*)  (ws);                        // 16 MB
  u16*   PbfT  = (u16*)  (ws + (16u << 20));          // 16 MB
  u16*   attnb = (u16*)  (ws + (32u << 20));          // 16 MB
  u16*   Wp    = (u16*)  (ws + (48u << 20));          // 768 KB packed fragments
  float* sbv   = (float*)(ws + (49u << 20));          // 128 KB

  prep_rows<<<8192, 256, 0, stream>>>(P, wi, Pbf, sbv);
  prep_w<<<48, 256, 0, stream>>>(w1, w2, w3, Wp);
  transpose_p<<<dim3(16, 4, 32), 256, 0, stream>>>(Pbf, PbfT);
  attn_kernel<<<512, 128, 0, stream>>>(P, wi, Pbf, PbfT, sbv, attnb);
  mlp_kernel<<<1024, 256, 0, stream>>>(Pbf, attnb, Wp, b1, b2, b3, out);
}

// Round 14
// 124.293 us; speedup vs baseline: 1.9854x; 1.9854x over previous
//
#include <hip/hip_runtime.h>
#include <hip/hip_bf16.h>

typedef unsigned short u16;
typedef unsigned int   u32;

using bf16x8 = __attribute__((ext_vector_type(8))) short;  // 8 bf16 in 4 VGPRs
using f32x4  = __attribute__((ext_vector_type(4))) float;  // MFMA accumulator

#define NB 32
#define NP 1024
#define ND 256

__device__ __forceinline__ u16 f2bf(float x){
  u32 u = __float_as_uint(x);
  u += 0x7FFFu + ((u >> 16) & 1u);   // round-to-nearest-even
  return (u16)(u >> 16);
}

__device__ __forceinline__ float bf2f(u16 x){
  return __uint_as_float((u32)x << 16);
}

__device__ __forceinline__ void glds16(const void* g, void* l){
  __builtin_amdgcn_global_load_lds((const __attribute__((address_space(1))) void*)g,
                                   (__attribute__((address_space(3))) void*)l, 16, 0, 0);
}

// ---------------- prep 1: Pbf = bf16(P), sbv[row] = P[row,:] . wb ----------------
__global__ void prep_rows(const float* __restrict__ P, const float* __restrict__ wi,
                          u16* __restrict__ Pbf, float* __restrict__ sbv){
  const int row  = blockIdx.x * 4 + (threadIdx.x >> 6);   // one wave per row
  const int lane = threadIdx.x & 63;
  const float4 p  = *(const float4*)(P  + (size_t)row * ND + lane * 4);
  const float4 wb = *(const float4*)(wi + ND + lane * 4);  // wb = wi[256:512]
  ushort4 pb;
  pb.x = f2bf(p.x); pb.y = f2bf(p.y); pb.z = f2bf(p.z); pb.w = f2bf(p.w);
  *(ushort4*)(Pbf + (size_t)row * ND + lane * 4) = pb;
  float s = p.x*wb.x + p.y*wb.y + p.z*wb.z + p.w*wb.w;
  #pragma unroll
  for (int m = 1; m < 64; m <<= 1) s += __shfl_xor(s, m, 64);
  if (lane == 0) sbv[row] = s;
}

// ------- prep 2: pack W fragment-major: Wp[((t*16+c)*64+lane)*8 + e] -------------
__global__ void prep_w(const float* __restrict__ w1, const float* __restrict__ w2,
                       const float* __restrict__ w3, u16* __restrict__ Wp){
  const int t = blockIdx.x;                       // 0..47
  const float* w = (t < 16) ? w1 : ((t < 32) ? w2 : w3);
  const int tid = threadIdx.x;
  #pragma unroll
  for (int j = 0; j < 4; ++j){
    int item = tid + 256 * j;                     // c*64 + lane
    int c = item >> 6, lane = item & 63;
    int ncol = ((t & 15) << 4) + (lane & 15);
    int k0 = 32 * c + 8 * (lane >> 4);
    u16 tmp[8];
    #pragma unroll
    for (int e = 0; e < 8; ++e) tmp[e] = f2bf(w[(size_t)(k0 + e) * 256 + ncol]);
    *(uint4*)(Wp + ((size_t)(t * 16 + c) * 64 + lane) * 8) = *(uint4*)tmp;
  }
}

// ---------------- prep 3: PbfT[b][d][j] = Pbf[b][j][d] (64x64 LDS tiles) ---------
__global__ void transpose_p(const u16* __restrict__ Pbf, u16* __restrict__ PbfT){
  const int b = blockIdx.z, jt = blockIdx.x, dt = blockIdx.y;
  __shared__ u16 T[64][72];
  const int tid = threadIdx.x;
  #pragma unroll
  for (int it = 0; it < 2; ++it){
    int cc = tid + 256 * it;               // 0..511: 64 j-rows x 8 chunks
    int j = cc >> 3, c8 = cc & 7;
    uint4 v = *(const uint4*)(Pbf + ((size_t)b * NP + jt * 64 + j) * ND + dt * 64 + c8 * 8);
    *(uint4*)&T[j][c8 * 8] = v;
  }
  __syncthreads();
  #pragma unroll
  for (int it = 0; it < 2; ++it){
    int cc = tid + 256 * it;               // 64 d-rows x 8 chunks
    int d = cc >> 3, c8 = cc & 7;
    u16 tmp[8];
    #pragma unroll
    for (int k = 0; k < 8; ++k) tmp[k] = T[c8 * 8 + k][d];
    *(uint4*)(PbfT + ((size_t)b * ND + dt * 64 + d) * NP + jt * 64 + c8 * 8) = *(uint4*)tmp;
  }
}

// -------- attention: r10 structure, KBLK=32 -> 37KB LDS -> 3-4 blocks/CU ---------
// r10 (KBLK=64, 74.7KB, 2 blocks/CU) showed no saturated pipe: ~45us of stall at
// 2 waves/SIMD. This round changes ONE axis: KBLK 64->32 with the SAME layouts,
// staged bytes, MFMA count, and register footprint -> 12-16 waves/CU.
// Bank derivations (validated rule: b128 conflict-free iff quad=(addr/16)%8
// bijects (lo&7) at fixed hi):
//   K: phys = j*512 + 16*(ck ^ (j&7)), j=0..31   -> quad (4c+hi)^(lo&7): clean
//   V: phys = d*64  + 16*(kc ^ ((d>>1)&3))       -> quad 4(lo&1)+(hi^((lo>>1)&3)):
//      bijective over lo&7 (r11's d&3 variant was NOT - it ignored bit 2)
//   Sp[4][16][40]: read quad (5lo+hi)%8 bijective; write 4-way (as r10, accepted)
// glds sources = whole-row 16B permutations (coalesced). Split barriers as r10.
// VGPR ~116 natural; __launch_bounds__(256,3) caps at 170 - safe (r5 lesson:
// never cap below accumulator footprint).
__launch_bounds__(256, 3)
__global__ void attn_kernel(const float* __restrict__ P, const float* __restrict__ wi,
                            const u16* __restrict__ Pbf, const u16* __restrict__ PbfT,
                            const float* __restrict__ sbv, u16* __restrict__ attnb){
  const int p    = blockIdx.x;
  const int bid  = ((p & 7) << 6) | (p >> 3);     // 64 consecutive bids per XCD
  const int b    = bid >> 4;
  const int q0   = (bid & 15) << 6;
  const int tid  = threadIdx.x;
  const int wave = tid >> 6, lane = tid & 63, lo = lane & 15, hi = lane >> 4;

  __shared__ __align__(16) u16 KtA[32 * 256];     // 16 KB
  __shared__ __align__(16) u16 VtA[256 * 32];     // 16 KB
  __shared__ __align__(16) u16 Sp[4][16][40];     // 5 KB
  char* KtB = (char*)KtA;
  char* VtB = (char*)VtA;

  // ---- Q fragments (A-operand): q = P * wc, bf16, in regs ----
  bf16x8 qf[8];
  {
    const int qrow = q0 + wave * 16 + lo;
    const float* prow = P  + ((size_t)b * NP + qrow) * ND;
    const float* wcp  = wi + 512;
    #pragma unroll
    for (int c = 0; c < 8; ++c){
      const int d0 = 32 * c + 8 * hi;
      float4 a  = *(const float4*)(prow + d0);
      float4 a2 = *(const float4*)(prow + d0 + 4);
      float4 wa  = *(const float4*)(wcp + d0);
      float4 wa2 = *(const float4*)(wcp + d0 + 4);
      bf16x8 q;
      q[0]=(short)f2bf(a.x*wa.x);  q[1]=(short)f2bf(a.y*wa.y);
      q[2]=(short)f2bf(a.z*wa.z);  q[3]=(short)f2bf(a.w*wa.w);
      q[4]=(short)f2bf(a2.x*wa2.x); q[5]=(short)f2bf(a2.y*wa2.y);
      q[6]=(short)f2bf(a2.z*wa2.z); q[7]=(short)f2bf(a2.w*wa2.w);
      qf[c] = q;
    }
  }

  f32x4 of[16];
  #pragma unroll
  for (int t = 0; t < 16; ++t) of[t] = (f32x4){0.f,0.f,0.f,0.f};
  float mx[4] = {-1e30f,-1e30f,-1e30f,-1e30f};
  float ls[4] = {0.f,0.f,0.f,0.f};

  const u16* kslab = Pbf  + (size_t)b * NP * ND;   // row-major [j][d]
  const u16* vslab = PbfT + (size_t)b * ND * NP;   // d-major  [d][j]

  auto stageK = [&](int kt){
    const int kbase = kt * 32;
    #pragma unroll
    for (int it = 0; it < 4; ++it){
      int off = it * 4096 + tid * 16;             // linear LDS dest byte
      int j   = off >> 9;                          // key row 0..31
      int ck  = ((off >> 4) & 31) ^ (j & 7);
      glds16((const char*)(kslab + (size_t)(kbase + j) * ND + ck * 8), KtB + off);
    }
  };
  auto stageV = [&](int kt){
    const int kbase = kt * 32;
    #pragma unroll
    for (int it = 0; it < 4; ++it){
      int off = it * 4096 + tid * 16;
      int pidx = off >> 4;                         // 16B unit index
      int d   = pidx >> 2;                         // feature row 0..255
      int u   = pidx & 3;
      int kc  = u ^ ((d >> 1) & 3);
      glds16((const char*)(vslab + (size_t)d * NP + kbase + kc * 8), VtB + off);
    }
  };

  float sbc[2], sbn[2];
  stageK(0);
  stageV(0);
  #pragma unroll
  for (int nt = 0; nt < 2; ++nt) sbc[nt] = sbv[(size_t)b * NP + nt * 16 + lo];
  __syncthreads();                                 // drain: K0,V0 valid

  for (int kt = 0; kt < 32; ++kt){
    // ---- S = Q K^T (2 col-tiles; V(kt) glds drained by this iter's entry) ----
    f32x4 s[2];
    #pragma unroll
    for (int nt = 0; nt < 2; ++nt){
      f32x4 acc = (f32x4){0.f,0.f,0.f,0.f};
      #pragma unroll
      for (int c = 0; c < 8; ++c){
        int j  = nt * 16 + lo;
        int ad = j * 512 + (((4 * c + hi) ^ (j & 7)) << 4);
        bf16x8 kf = *(const bf16x8*)(KtB + ad);
        acc = __builtin_amdgcn_mfma_f32_16x16x32_bf16(qf[c], kf, acc, 0, 0, 0);
      }
      s[nt] = acc;
      float sv = sbc[nt];
      #pragma unroll
      for (int r = 0; r < 4; ++r) s[nt][r] += sv;
    }

    __syncthreads();                  // barrier1: all waves done reading Kt
    if (kt < 31) stageK(kt + 1);      // in flight across softmax+PV; drains at b2

    // ---- deferred online softmax ----
    float md = -1e30f;
    #pragma unroll
    for (int nt = 0; nt < 2; ++nt)
      #pragma unroll
      for (int r = 0; r < 4; ++r) md = fmaxf(md, s[nt][r] - mx[r]);
    if (!__all(md <= 8.f)){
      // slow path: proper row maxima + rescale (tile 0, rare after)
      float scale[4];
      #pragma unroll
      for (int r = 0; r < 4; ++r){
        float v = fmaxf(s[0][r], s[1][r]);
        v = fmaxf(v, __shfl_xor(v, 1, 64));
        v = fmaxf(v, __shfl_xor(v, 2, 64));
        v = fmaxf(v, __shfl_xor(v, 4, 64));
        v = fmaxf(v, __shfl_xor(v, 8, 64));
        float mnew = fmaxf(mx[r], v);
        scale[r] = __expf(mx[r] - mnew);
        mx[r] = mnew;
        ls[r] *= scale[r];
      }
      #pragma unroll
      for (int t = 0; t < 16; ++t)
        #pragma unroll
        for (int r = 0; r < 4; ++r) of[t][r] *= scale[r];
    }
    // common path: exp, per-lane partial sums, repack (p bounded by e^8)
    #pragma unroll
    for (int nt = 0; nt < 2; ++nt)
      #pragma unroll
      for (int r = 0; r < 4; ++r){
        float pv = __expf(s[nt][r] - mx[r]);
        ls[r] += pv;
        Sp[wave][4 * hi + r][16 * nt + lo] = f2bf(pv);
      }

    // ---- O += P V (single K=32 MFMA per d-tile; Sp is within-wave) ----
    {
      bf16x8 pa = *(const bf16x8*)&Sp[wave][lo][8 * hi];
      #pragma unroll
      for (int t = 0; t < 16; ++t){
        int d  = 16 * t + lo;
        int ad = d * 64 + ((hi ^ ((d >> 1) & 3)) << 4);
        bf16x8 vb = *(const bf16x8*)(VtB + ad);
        of[t] = __builtin_amdgcn_mfma_f32_16x16x32_bf16(pa, vb, of[t], 0, 0, 0);
      }
    }

    __syncthreads();                  // barrier2: Vt reads done; drains K(t+1)
    if (kt < 31){
      stageV(kt + 1);                 // in flight across next QK^T; drains at b1
      #pragma unroll
      for (int nt = 0; nt < 2; ++nt)
        sbn[nt] = sbv[(size_t)b * NP + (kt + 1) * 32 + nt * 16 + lo];
      sbc[0] = sbn[0]; sbc[1] = sbn[1];
    }
  }

  // ---- epilogue: one cross-lane ls reduce, O /= l, store bf16 ----
  #pragma unroll
  for (int r = 0; r < 4; ++r){
    ls[r] += __shfl_xor(ls[r], 1, 64);
    ls[r] += __shfl_xor(ls[r], 2, 64);
    ls[r] += __shfl_xor(ls[r], 4, 64);
    ls[r] += __shfl_xor(ls[r], 8, 64);
  }
  const int qrow = q0 + wave * 16;
  #pragma unroll
  for (int t = 0; t < 16; ++t){
    #pragma unroll
    for (int r = 0; r < 4; ++r){
      float o = of[t][r] / ls[r];
      attnb[((size_t)b * NP + qrow + 4 * hi + r) * ND + 16 * t + lo] = f2bf(o);
    }
  }
}

// ---------------- MLP: proper GEMM, M-tile 128, fused gate epilogue --------------
// NOTE: acc[3][8] = 96 VGPRs of accumulator. __launch_bounds__ min-waves MUST stay
// at 2 (VGPR budget 256): round-5's (256,4) capped the allocator at 64 VGPR and
// spilled all accumulators to scratch (WRITE_SIZE 33 -> 325 MB, 18 -> 136 us).
__launch_bounds__(256, 2)
__global__ void mlp_kernel(const u16* __restrict__ Pbf, const u16* __restrict__ attnb,
                           const u16* __restrict__ Wp,
                           const float* __restrict__ b1, const float* __restrict__ b2,
                           const float* __restrict__ b3, float* __restrict__ out){
  const int p    = blockIdx.x;
  const int swz  = ((p & 7) << 7) | (p >> 3);     // XCD-chunked
  const int mt   = swz >> 2, cg = swz & 3;
  const int tid  = threadIdx.x;
  const int wave = tid >> 6, lane = tid & 63, lo = lane & 15, hi = lane >> 4;
  const int tq   = 4 * cg + wave;
  const int m0   = mt * 128;

  __shared__ __align__(16) u16 Ab[2][128 * 64];   // 2 x 16 KB, swizzled

  f32x4 acc[3][8];
  #pragma unroll
  for (int e = 0; e < 3; ++e)
    #pragma unroll
    for (int m = 0; m < 8; ++m) acc[e][m] = (f32x4){0.f,0.f,0.f,0.f};

  auto stage = [&](int s, int buf){
    const u16* xs = (s < 4) ? (Pbf   + (size_t)m0 * ND + s * 64)
                            : (attnb + (size_t)m0 * ND + (s - 4) * 64);
    char* dst = (char*)Ab[buf];
    #pragma unroll
    for (int it = 0; it < 4; ++it){
      int off = it * 4096 + wave * 1024 + lane * 16;   // physical LDS byte
      int row = off >> 7;                               // 128B per row
      int cl  = (off & 127) ^ ((row & 7) << 4);         // logical byte in row
      glds16((const char*)(xs + (size_t)row * ND) + cl, dst + it * 4096 + wave * 1024);
    }
  };

  stage(0, 0);
  __syncthreads();

  for (int s = 0; s < 8; ++s){
    if (s < 7) stage(s + 1, (s + 1) & 1);
    const char* ab = (const char*)Ab[s & 1];
    #pragma unroll
    for (int cc = 0; cc < 2; ++cc){
      const int c = 2 * s + cc;
      bf16x8 wf[3];
      #pragma unroll
      for (int e = 0; e < 3; ++e)
        wf[e] = *(const bf16x8*)(Wp + ((size_t)((tq + 16 * e) * 16 + c) * 64 + lane) * 8);
      #pragma unroll
      for (int m = 0; m < 8; ++m){
        int row = 16 * m + lo;
        bf16x8 af = *(const bf16x8*)(ab + row * 128 + ((64 * cc + 16 * hi) ^ ((row & 7) << 4)));
        #pragma unroll
        for (int e = 0; e < 3; ++e)
          acc[e][m] = __builtin_amdgcn_mfma_f32_16x16x32_bf16(af, wf[e], acc[e][m], 0, 0, 0);
      }
    }
    __syncthreads();
  }

  // ---- fused gate epilogue ----
  const int d = 16 * tq + lo;
  const float bb1 = b1[d], bb2 = b2[d], bb3 = b3[d];
  #pragma unroll
  for (int m = 0; m < 8; ++m){
    #pragma unroll
    for (int r = 0; r < 4; ++r){
      const int row = m0 + 16 * m + 4 * hi + r;
      float y1 = acc[0][m][r] + bb1;
      float y2 = acc[1][m][r] + bb2;
      float y3 = acc[2][m][r] + bb3;
      float pv = bf2f(Pbf[(size_t)row * ND + d]);
      float e2 = __expf(2.f * y1);
      float z  = (e2 - 1.f) / (e2 + 1.f);          // tanh
      float rr = 1.f / (1.f + __expf(-y2));        // sigmoid
      float ff = 1.f / (1.f + __expf(-y3));        // sigmoid
      out[(size_t)row * ND + d] = rr * pv + ff * z;
    }
  }
}

extern "C" void kernel_launch(void* const* d_in, const int* in_sizes, int n_in,
                              void* d_out, int out_size, void* d_ws, size_t ws_size,
                              hipStream_t stream){
  const float* P  = (const float*)d_in[0];
  const float* wi = (const float*)d_in[1];
  const float* w1 = (const float*)d_in[2];
  const float* w2 = (const float*)d_in[3];
  const float* w3 = (const float*)d_in[4];
  const float* b1 = (const float*)d_in[5];
  const float* b2 = (const float*)d_in[6];
  const float* b3 = (const float*)d_in[7];
  float* out = (float*)d_out;

  char* ws = (char*)d_ws;
  u16*   Pbf   = (u16*)  (ws);                        // 16 MB
  u16*   PbfT  = (u16*)  (ws + (16u << 20));          // 16 MB
  u16*   attnb = (u16*)  (ws + (32u << 20));          // 16 MB
  u16*   Wp    = (u16*)  (ws + (48u << 20));          // 768 KB packed fragments
  float* sbv   = (float*)(ws + (49u << 20));          // 128 KB

  prep_rows<<<8192, 256, 0, stream>>>(P, wi, Pbf, sbv);
  prep_w<<<48, 256, 0, stream>>>(w1, w2, w3, Wp);
  transpose_p<<<dim3(16, 4, 32), 256, 0, stream>>>(Pbf, PbfT);
  attn_kernel<<<512, 256, 0, stream>>>(P, wi, Pbf, PbfT, sbv, attnb);
  mlp_kernel<<<1024, 256, 0, stream>>>(Pbf, attnb, Wp, b1, b2, b3, out);
}